// Round 2
// baseline (382.413 us; speedup 1.0000x reference)
//
#include <hip/hip_runtime.h>
#include <stdint.h>

#define DIM    128
#define HEADS  8
#define INNER  1024
#define HIDDEN 512
#define BATCH  8
#define SEQ    1024
#define ROWS   8192   // BATCH*SEQ

typedef __attribute__((ext_vector_type(8))) short bf16x8;
typedef __attribute__((ext_vector_type(4))) float f32x4;
typedef __attribute__((ext_vector_type(4))) unsigned short u16x4;

static __device__ __forceinline__ float b2f(unsigned short u) {
    union { float f; unsigned int i; } v; v.i = ((unsigned int)u) << 16; return v.f;
}
static __device__ __forceinline__ unsigned short f2b(float f) {
    union { float f; unsigned int i; } v; v.f = f;
    unsigned int x = v.i;
    return (unsigned short)((x + 0x7fffu + ((x >> 16) & 1u)) >> 16);
}

// ---------------- f32 -> bf16 weight conversion ----------------
__global__ __launch_bounds__(256)
void cvt_kernel(const float* __restrict__ in, unsigned short* __restrict__ out, int n4)
{
    const int i = blockIdx.x * 256 + threadIdx.x;
    if (i < n4) {
        const float4 v = ((const float4*)in)[i];
        u16x4 o;
        o[0] = f2b(v.x); o[1] = f2b(v.y); o[2] = f2b(v.z); o[3] = f2b(v.w);
        ((u16x4*)out)[i] = o;
    }
}

// ---------------- LayerNorm: one wave per 128-elem row (f32 in, bf16 out) ----------------
__global__ __launch_bounds__(256)
void ln_kernel(const float* __restrict__ in,
               const float* __restrict__ w,
               const float* __restrict__ b,
               unsigned short* __restrict__ out, int rows)
{
    const int wave = threadIdx.x >> 6;
    const int lane = threadIdx.x & 63;
    const int row  = blockIdx.x * 4 + wave;
    if (row >= rows) return;

    const float2 xv = *(const float2*)(in + (size_t)row*DIM + lane*2);
    float x0 = xv.x, x1 = xv.y;

    float s = x0 + x1;
    float q = x0*x0 + x1*x1;
    #pragma unroll
    for (int off = 32; off > 0; off >>= 1) {
        s += __shfl_xor(s, off);
        q += __shfl_xor(q, off);
    }
    const float mu  = s * (1.0f/128.0f);
    const float var = q * (1.0f/128.0f) - mu*mu;
    const float rs  = rsqrtf(var + 1e-5f);

    const float2 wv = *(const float2*)(w + lane*2);
    const float2 bv = *(const float2*)(b + lane*2);
    unsigned short o0 = f2b((x0 - mu) * rs * wv.x + bv.x);
    unsigned short o1 = f2b((x1 - mu) * rs * wv.y + bv.y);
    *(unsigned int*)(out + (size_t)row*DIM + lane*2) = (unsigned int)o0 | ((unsigned int)o1 << 16);
}

// ---------------- Generic TN GEMM: C(MxN) = A(MxK) * W(NxK)^T ----------------
// block = 4 waves stacked in M; wave tile = 16(M) x 64(N)
// EPI: 0=q scatter, 1=kv scatter (k + v-transposed), 2=proj(+bias,*ls1,+x -> f32),
//      3=fc1(+bias,relu -> bf16), 4=fc2(+bias,*ls2,+x1 -> f32 out)
template<int K, int EPI>
__global__ __launch_bounds__(256)
void gemm_kernel(const unsigned short* __restrict__ A,
                 const unsigned short* __restrict__ W,
                 void* __restrict__ out0, void* __restrict__ out1,
                 const float* __restrict__ bias,
                 const float* __restrict__ gamma,
                 const float* __restrict__ resid)
{
    const int lane = threadIdx.x & 63;
    const int wave = threadIdx.x >> 6;
    const int g    = lane >> 4;
    const int c16  = lane & 15;
    const int mb   = blockIdx.y * 64 + wave * 16;
    const int nb   = blockIdx.x * 64;

    f32x4 acc[4];
    #pragma unroll
    for (int t = 0; t < 4; ++t) acc[t] = (f32x4){0.f, 0.f, 0.f, 0.f};

    const unsigned short* arow = A + (size_t)(mb + c16) * K;
    #pragma unroll 4
    for (int ks = 0; ks < K/32; ++ks) {
        const int koff = ks*32 + g*8;
        bf16x8 af = *(const bf16x8*)(arow + koff);
        #pragma unroll
        for (int t = 0; t < 4; ++t) {
            bf16x8 wf = *(const bf16x8*)(W + (size_t)(nb + t*16 + c16) * K + koff);
            acc[t] = __builtin_amdgcn_mfma_f32_16x16x32_bf16(af, wf, acc[t], 0, 0, 0);
        }
    }

    #pragma unroll
    for (int t = 0; t < 4; ++t) {
        #pragma unroll
        for (int r = 0; r < 4; ++r) {
            const int row = mb + g*4 + r;
            const int col = nb + t*16 + c16;
            const float v = acc[t][r];
            if (EPI == 0) {
                const int bb = row >> 10, n = row & 1023, hh = col >> 7, p = col & 127;
                ((unsigned short*)out0)[(((size_t)(bb*HEADS + hh))*SEQ + n)*DIM + p] = f2b(v);
            } else if (EPI == 1) {
                const int bb = row >> 10, m = row & 1023;
                if (col < INNER) {
                    const int hh = col >> 7, p = col & 127;
                    ((unsigned short*)out0)[(((size_t)(bb*HEADS + hh))*SEQ + m)*DIM + p] = f2b(v);
                } else {
                    const int c2 = col - INNER;
                    const int hh = c2 >> 7, p = c2 & 127;
                    ((unsigned short*)out1)[(((size_t)(bb*HEADS + hh))*DIM + p)*SEQ + m] = f2b(v);
                }
            } else if (EPI == 2) {
                const float xv = resid[(size_t)row*DIM + col];
                ((float*)out0)[(size_t)row*DIM + col] = xv + (v + bias[col]) * gamma[col];
            } else if (EPI == 3) {
                const float hv = v + bias[col];
                ((unsigned short*)out0)[(size_t)row*HIDDEN + col] = f2b(fmaxf(hv, 0.f));
            } else {
                const float ov = resid[(size_t)row*DIM + col] + (v + bias[col]) * gamma[col];
                ((float*)out0)[(size_t)row*DIM + col] = ov;
            }
        }
    }
}

// ---------------- Flash attention (swapped QK^T), 4 waves x 16 Q-rows ----------------
__global__ __launch_bounds__(256)
void attn_kernel(const unsigned short* __restrict__ qbuf,  // (B,H,N,P)
                 const unsigned short* __restrict__ kbuf,  // (B,H,M,P)
                 const unsigned short* __restrict__ vtbuf, // (B,H,P,M)
                 unsigned short* __restrict__ obuf)        // (B,N,INNER)
{
    __shared__ uint2 pls[4][2][128];   // per-wave P scratch (16 rows x 32 m bf16), dbuf

    const int lane = threadIdx.x & 63;
    const int wave = threadIdx.x >> 6;
    const int g    = lane >> 4;
    const int c16  = lane & 15;
    const int bh   = blockIdx.x >> 4;
    const int nblk = blockIdx.x & 15;
    const int n0   = nblk * 64 + wave * 16;
    const int bb   = bh >> 3, hh = bh & 7;

    const unsigned short* Q  = qbuf  + (size_t)bh * SEQ * DIM;
    const unsigned short* Kp = kbuf  + (size_t)bh * SEQ * DIM;
    const unsigned short* Vt = vtbuf + (size_t)bh * DIM * SEQ;

    bf16x8 qf[4];
    #pragma unroll
    for (int ks = 0; ks < 4; ++ks)
        qf[ks] = *(const bf16x8*)(Q + (size_t)(n0 + c16)*DIM + ks*32 + g*8);

    f32x4 oacc[8];
    #pragma unroll
    for (int pc = 0; pc < 8; ++pc) oacc[pc] = (f32x4){0.f,0.f,0.f,0.f};
    float mi = -1e30f, li = 0.f;
    const float scale = 0.08838834764831845f;  // 1/sqrt(128)

    for (int it = 0; it < 32; ++it) {
        const int mc = it * 32;
        // S^T = K_chunk * Q^T  -> lane holds S[n=c16][m = 16s + 4g + r]
        f32x4 st[2];
        #pragma unroll
        for (int s = 0; s < 2; ++s) {
            f32x4 a = (f32x4){0.f,0.f,0.f,0.f};
            #pragma unroll
            for (int ks = 0; ks < 4; ++ks) {
                bf16x8 kf = *(const bf16x8*)(Kp + (size_t)(mc + s*16 + c16)*DIM + ks*32 + g*8);
                a = __builtin_amdgcn_mfma_f32_16x16x32_bf16(kf, qf[ks], a, 0, 0, 0);
            }
            st[s] = a;
        }
        float cmax = -1e30f;
        #pragma unroll
        for (int s = 0; s < 2; ++s)
            #pragma unroll
            for (int r = 0; r < 4; ++r) { st[s][r] *= scale; cmax = fmaxf(cmax, st[s][r]); }
        cmax = fmaxf(cmax, __shfl_xor(cmax, 16));
        cmax = fmaxf(cmax, __shfl_xor(cmax, 32));
        const float mnew  = fmaxf(mi, cmax);
        const float alpha = __expf(mi - mnew);

        float psum = 0.f;
        uint2 pw[2];
        #pragma unroll
        for (int s = 0; s < 2; ++s) {
            float p0 = __expf(st[s][0] - mnew), p1 = __expf(st[s][1] - mnew);
            float p2 = __expf(st[s][2] - mnew), p3 = __expf(st[s][3] - mnew);
            psum += (p0 + p1) + (p2 + p3);
            pw[s].x = (unsigned int)f2b(p0) | ((unsigned int)f2b(p1) << 16);
            pw[s].y = (unsigned int)f2b(p2) | ((unsigned int)f2b(p3) << 16);
        }
        psum += __shfl_xor(psum, 16);
        psum += __shfl_xor(psum, 32);
        li = li * alpha + psum;
        mi = mnew;

        const int db = it & 1;
        pls[wave][db][c16*8 + 0*4 + g] = pw[0];
        pls[wave][db][c16*8 + 1*4 + g] = pw[1];

        // rescale o accumulator (rows n = 4g + r; stats live at lane index n)
        float ar[4];
        #pragma unroll
        for (int r = 0; r < 4; ++r) ar[r] = __shfl(alpha, g*4 + r);
        #pragma unroll
        for (int pc = 0; pc < 8; ++pc)
            #pragma unroll
            for (int r = 0; r < 4; ++r) oacc[pc][r] *= ar[r];

        // per-wave LDS scratch: in-wave ds_write->ds_read ordering handled by compiler
        const unsigned short* pbase = (const unsigned short*)&pls[wave][db][0];
        bf16x8 pa = *(const bf16x8*)(pbase + c16*32 + g*8);
        #pragma unroll
        for (int pc = 0; pc < 8; ++pc) {
            bf16x8 vf = *(const bf16x8*)(Vt + (size_t)(pc*16 + c16)*SEQ + mc + g*8);
            oacc[pc] = __builtin_amdgcn_mfma_f32_16x16x32_bf16(pa, vf, oacc[pc], 0, 0, 0);
        }
    }

    float lr[4];
    #pragma unroll
    for (int r = 0; r < 4; ++r) lr[r] = 1.f / __shfl(li, g*4 + r);
    #pragma unroll
    for (int pc = 0; pc < 8; ++pc)
        #pragma unroll
        for (int r = 0; r < 4; ++r) {
            const int n = n0 + g*4 + r;
            obuf[((size_t)bb*SEQ + n)*INNER + hh*DIM + pc*16 + c16] = f2b(oacc[pc][r] * lr[r]);
        }
}

// ---------------- launch ----------------
extern "C" void kernel_launch(void* const* d_in, const int* in_sizes, int n_in,
                              void* d_out, int out_size, void* d_ws, size_t ws_size,
                              hipStream_t stream)
{
    const float* x         = (const float*)d_in[0];
    const float* y         = (const float*)d_in[1];
    const float* norm_x_w  = (const float*)d_in[2];
    const float* norm_x_b  = (const float*)d_in[3];
    const float* norm_y_w  = (const float*)d_in[4];
    const float* norm_y_b  = (const float*)d_in[5];
    const float* q_w       = (const float*)d_in[6];
    const float* kv_w      = (const float*)d_in[7];
    const float* proj_w    = (const float*)d_in[8];
    const float* proj_b    = (const float*)d_in[9];
    const float* ls1_gamma = (const float*)d_in[10];
    const float* norm_o_w  = (const float*)d_in[11];
    const float* norm_o_b  = (const float*)d_in[12];
    const float* fc1_w     = (const float*)d_in[13];
    const float* fc1_b     = (const float*)d_in[14];
    const float* fc2_w     = (const float*)d_in[15];
    const float* fc2_b     = (const float*)d_in[16];
    const float* ls2_gamma = (const float*)d_in[17];

    char* ws = (char*)d_ws;
    size_t off = 0;
    auto alloc = [&](size_t bytes) {
        void* p = ws + off;
        off += (bytes + 255) & ~(size_t)255;
        return p;
    };
    unsigned short* xn  = (unsigned short*)alloc((size_t)ROWS*DIM*2);
    unsigned short* yn  = (unsigned short*)alloc((size_t)ROWS*DIM*2);
    unsigned short* qb  = (unsigned short*)alloc((size_t)ROWS*INNER*2);
    unsigned short* kb  = (unsigned short*)alloc((size_t)ROWS*INNER*2);
    unsigned short* vtb = (unsigned short*)alloc((size_t)ROWS*INNER*2);
    unsigned short* ob  = (unsigned short*)alloc((size_t)ROWS*INNER*2);
    float*          x1  = (float*)alloc((size_t)ROWS*DIM*4);
    unsigned short* hin = (unsigned short*)alloc((size_t)ROWS*DIM*2);
    unsigned short* h1  = (unsigned short*)alloc((size_t)ROWS*HIDDEN*2);
    unsigned short* wq   = (unsigned short*)alloc((size_t)INNER*DIM*2);
    unsigned short* wkv  = (unsigned short*)alloc((size_t)2*INNER*DIM*2);
    unsigned short* wpr  = (unsigned short*)alloc((size_t)DIM*INNER*2);
    unsigned short* wf1  = (unsigned short*)alloc((size_t)HIDDEN*DIM*2);
    unsigned short* wf2  = (unsigned short*)alloc((size_t)DIM*HIDDEN*2);

    // 0) convert weights f32 -> bf16
    cvt_kernel<<<dim3(INNER*DIM/1024),    256, 0, stream>>>(q_w,    wq,  INNER*DIM/4);
    cvt_kernel<<<dim3(2*INNER*DIM/1024),  256, 0, stream>>>(kv_w,   wkv, 2*INNER*DIM/4);
    cvt_kernel<<<dim3(DIM*INNER/1024),    256, 0, stream>>>(proj_w, wpr, DIM*INNER/4);
    cvt_kernel<<<dim3(HIDDEN*DIM/1024),   256, 0, stream>>>(fc1_w,  wf1, HIDDEN*DIM/4);
    cvt_kernel<<<dim3(DIM*HIDDEN/1024),   256, 0, stream>>>(fc2_w,  wf2, DIM*HIDDEN/4);

    // 1) LayerNorms of x and y  (f32 in -> bf16 out)
    ln_kernel<<<dim3(ROWS/4), 256, 0, stream>>>(x, norm_x_w, norm_x_b, xn, ROWS);
    ln_kernel<<<dim3(ROWS/4), 256, 0, stream>>>(y, norm_y_w, norm_y_b, yn, ROWS);

    // 2) q / kv projections
    gemm_kernel<128, 0><<<dim3(INNER/64, ROWS/64), 256, 0, stream>>>(
        xn, wq, qb, nullptr, nullptr, nullptr, nullptr);
    gemm_kernel<128, 1><<<dim3(2*INNER/64, ROWS/64), 256, 0, stream>>>(
        yn, wkv, kb, vtb, nullptr, nullptr, nullptr);

    // 3) attention
    attn_kernel<<<dim3(BATCH*HEADS*16), 256, 0, stream>>>(qb, kb, vtb, ob);

    // 4) proj + bias + ls1*resid(x,f32) -> x1 (f32)
    gemm_kernel<1024, 2><<<dim3(DIM/64, ROWS/64), 256, 0, stream>>>(
        ob, wpr, x1, nullptr, proj_b, ls1_gamma, x);

    // 5) LN(x1) -> hin (bf16)
    ln_kernel<<<dim3(ROWS/4), 256, 0, stream>>>(x1, norm_o_w, norm_o_b, hin, ROWS);

    // 6) fc1 + relu -> h1 (bf16)
    gemm_kernel<128, 3><<<dim3(HIDDEN/64, ROWS/64), 256, 0, stream>>>(
        hin, wf1, h1, nullptr, fc1_b, nullptr, nullptr);

    // 7) fc2 + bias + ls2*resid(x1,f32) -> d_out (f32)
    gemm_kernel<512, 4><<<dim3(DIM/64, ROWS/64), 256, 0, stream>>>(
        h1, wf2, d_out, nullptr, fc2_b, ls2_gamma, x1);
}